// Round 2
// baseline (244.004 us; speedup 1.0000x reference)
//
#include <hip/hip_runtime.h>
#include <math.h>

// DivMergedLayer1: reference collapses to out = x except 4 floats per row.
//   N=32, D=128, F=4096, B=8192. Flat row layout: x[b, n, d] -> xr[n*128 + d].
//   op  = xr[67]            (OP_START+OPCODE = 64+3, nibble row 0)
//   r60 = relu(60*op); inv60 = fp32(1/60)
//   P   = sum_{i=0..31} 2^i * xr[i*128 + 0]     (gate reads NIB_A = col 0 !)
//   delta_c[s] = -(r60 * xr[s]) * inv60    for s in {2,3,4,5}
//   delta_g[2] =  r60 * P * inv60
//   float64 path over d_i = (double)xr[i*128 + 1]   (NIB_B = col 1):
//     score_i = d_i > 0.5 ? log(max(d_i*2^i, 0.5)) : -60
//     mx = max_i score_i; sum_ex = sum_i exp(score_i - mx)
//     recip = exp(-mx)/max(sum_ex, 1e-30)
//   out[2] = x2 - r60*x2/60 + r60*P/60
//   out[3] = x3 - r60*x3/60 ; out[4] likewise
//   out[5] = x5 - r60*x5/60 + op*(float)recip
//   out elsewhere = x exactly (zero weight rows -> exact fp32 zeros in ref).
//
// Memory-bound: 128 MiB in + 128 MiB out -> ~42 us roofline at 6.3 TB/s.
// One block per row; wave 0 does the scalar math, all 256 threads stream
// 4 x float4 each.

#define DDIM 128
#define FDIM 4096

__global__ __launch_bounds__(256) void div_merged_kernel(
    const float* __restrict__ x, float* __restrict__ out) {
  const long long row = blockIdx.x;
  const float* __restrict__ xr = x + row * (long long)FDIM;
  float* __restrict__ orow = out + row * (long long)FDIM;
  const int t = threadIdx.x;

  __shared__ float s_fix[4];  // corrected out[2..5]

  if (t < 64) {
    const int lane = t;
    const bool active = lane < 32;
    double score = -60.0;
    double p = 0.0;
    if (active) {
      const double pw = (double)(1ULL << lane);     // 2^lane, exact
      const float va = xr[lane * DDIM + 0];         // NIB_A: gate sum
      const float vb = xr[lane * DDIM + 1];         // NIB_B: softmax path
      p = (double)va * pw;
      const double d = (double)vb;
      score = (d > 0.5) ? log(fmax(d * pw, 0.5)) : -60.0;
    }
    // 64-lane butterfly max (inactive lanes hold -60: only equals mx when all
    // real scores are -60, which matches the reference's max in that case).
    double mx = score;
#pragma unroll
    for (int off = 1; off < 64; off <<= 1)
      mx = fmax(mx, __shfl_xor(mx, off));
    // sum of exp(score - mx) over the 32 real lanes, and sum of 2^i * a_i
    double ex = active ? exp(score - mx) : 0.0;
#pragma unroll
    for (int off = 1; off < 64; off <<= 1) {
      ex += __shfl_xor(ex, off);
      p  += __shfl_xor(p, off);
    }
    if (lane == 0) {
      const float op    = xr[67];
      const float r60   = fmaxf(60.0f * op, 0.0f);
      const float inv60 = (float)(1.0 / 60.0);
      const double recip = exp(-mx) / fmax(ex, 1e-30);
      const float Pf = (float)p;
      const float x2 = xr[2], x3 = xr[3], x4v = xr[4], x5 = xr[5];
      const float dc2 = -((r60 * x2) * inv60);
      const float dc3 = -((r60 * x3) * inv60);
      const float dc4 = -((r60 * x4v) * inv60);
      const float dc5 = -((r60 * x5) * inv60);
      const float dg2 = (r60 * Pf) * inv60;
      s_fix[0] = x2 + (dc2 + dg2);
      s_fix[1] = x3 + dc3;
      s_fix[2] = x4v + dc4;
      s_fix[3] = (x5 + dc5) + op * (float)recip;
    }
  }
  __syncthreads();

  const float4* __restrict__ x4 = (const float4*)xr;
  float4* __restrict__ o4 = (float4*)orow;
#pragma unroll
  for (int k = 0; k < 4; ++k) {
    const int idx = k * 256 + t;  // 1024 float4 per row
    float4 v = x4[idx];
    if (idx == 0) {
      v.z = s_fix[0];  // flat 2
      v.w = s_fix[1];  // flat 3
    } else if (idx == 1) {
      v.x = s_fix[2];  // flat 4
      v.y = s_fix[3];  // flat 5
    }
    o4[idx] = v;
  }
}

extern "C" void kernel_launch(void* const* d_in, const int* in_sizes, int n_in,
                              void* d_out, int out_size, void* d_ws, size_t ws_size,
                              hipStream_t stream) {
  const float* x = (const float*)d_in[0];  // (B, 32, 128) fp32
  float* out = (float*)d_out;              // (B, 32, 128) fp32
  const int rows = in_sizes[0] / FDIM;     // B = 8192
  div_merged_kernel<<<rows, 256, 0, stream>>>(x, out);
}